// Round 3
// baseline (1328.700 us; speedup 1.0000x reference)
//
#include <hip/hip_runtime.h>
#include <stdint.h>

// Problem: B=8, S=2048, H=1024. Inputs fp32, OUTPUT fp32 (ref computes in fp32;
// out_npz size 62MB proves fp32 — bf16 would compress to <33MB).
#define BD 8
#define SD 2048
#define HD 1024

typedef __bf16 bf16x8 __attribute__((ext_vector_type(8)));
typedef float f32x4 __attribute__((ext_vector_type(4)));
typedef unsigned short u16x8 __attribute__((ext_vector_type(8)));

__device__ __forceinline__ unsigned short f32_to_bf16(float f) {
  union { float f; unsigned u; } v; v.f = f;
  unsigned u = v.u;
  return (unsigned short)((u + 0x7FFFu + ((u >> 16) & 1u)) >> 16);  // RNE
}

// ---- cast one batch of x: fp32 [2048][1024] -> bf16 ----
__global__ __launch_bounds__(256) void cast_x_kernel(
    const float* __restrict__ x, unsigned short* __restrict__ xb) {
  int i = blockIdx.x * 256 + threadIdx.x;          // i indexes groups of 8
  const float4* xp = (const float4*)x;
  float4 a = xp[2*(size_t)i], b = xp[2*(size_t)i + 1];
  float v[8] = {a.x,a.y,a.z,a.w,b.x,b.y,b.z,b.w};
  u16x8 o;
#pragma unroll
  for (int j = 0; j < 8; j++) o[j] = f32_to_bf16(v[j]);
  *(u16x8*)(xb + (size_t)i*8) = o;
}

// ---- W [K][N] fp32 -> W^T bf16 [N][K], 3 weights via blockIdx.z ----
__global__ __launch_bounds__(256) void transpose_w_kernel(
    const float* __restrict__ Wq, const float* __restrict__ Wk,
    const float* __restrict__ Wv, unsigned short* __restrict__ wt) {
  __shared__ float tile[32][33];
  const int w = blockIdx.z;
  const float* W = (w == 0) ? Wq : ((w == 1) ? Wk : Wv);
  const int n0 = blockIdx.x * 32, k0 = blockIdx.y * 32;
  const int x = threadIdx.x, y = threadIdx.y;       // block (32,8)
  for (int j = 0; j < 32; j += 8)
    tile[y + j][x] = W[(size_t)(k0 + y + j) * HD + n0 + x];
  __syncthreads();
  unsigned short* dst = wt + (size_t)w * HD * HD;
  for (int j = 0; j < 32; j += 8)
    dst[(size_t)(n0 + y + j) * HD + k0 + x] = f32_to_bf16(tile[x][y + j]);
}

// ---- V_b [2048][1024] bf16 -> Vt [1024][2048] bf16 ----
__global__ __launch_bounds__(256) void transpose_v_kernel(
    const unsigned short* __restrict__ V, unsigned short* __restrict__ Vt) {
  __shared__ unsigned short tile[32][33];
  const int h0 = blockIdx.x * 32, s0 = blockIdx.y * 32;
  const int x = threadIdx.x, y = threadIdx.y;       // block (32,8)
  for (int j = 0; j < 32; j += 8)
    tile[y + j][x] = V[(size_t)(s0 + y + j) * HD + h0 + x];
  __syncthreads();
  for (int j = 0; j < 32; j += 8)
    Vt[(size_t)(h0 + y + j) * SD + s0 + x] = tile[x][y + j];
}

// ---- GEMM: C[M][N] = alpha * (A[M][K] * Bt[N][K]^T + bias[n]) ----
// 128x128 tile, BK=32, 4 waves (2x2), each wave 4x4 frags of 16x16x32 bf16 MFMA.
// Fragment mapping (AMD CDNA spec + learn_hip m89/m91 verified):
//   A: lane l holds row l&15, k = 8*(l>>4)+j
//   B: lane l holds col l&15 (= Bt row), same k
//   D: lane l, reg r -> row = 4*(l>>4)+r, col = l&15
template<int OUT_BF16>
__global__ __launch_bounds__(256, 2) void gemm_bt_kernel(
    const unsigned short* __restrict__ A, const unsigned short* __restrict__ Bt,
    const float* __restrict__ bias,
    float* __restrict__ Cf, unsigned short* __restrict__ Cb,
    int M, int N, int K, float alpha)
{
  const int LDT = 40;  // padded LDS row (ushorts): 80B stride, 2-way alias only
  __shared__ unsigned short As[128 * LDT];
  __shared__ unsigned short Bs[128 * LDT];
  const int tid  = threadIdx.x;
  const int lane = tid & 63;
  const int wid  = tid >> 6;
  const int wr   = wid >> 1, wc = wid & 1;
  const int m0 = blockIdx.y * 128, n0 = blockIdx.x * 128;

  f32x4 acc[4][4] = {};

  // staging: thread t covers tile row t>>1, 16-ushort half t&1
  const int sr = tid >> 1, shf = (tid & 1) * 16;
  const unsigned short* Ag = A  + (size_t)(m0 + sr) * K + shf;
  const unsigned short* Bg = Bt + (size_t)(n0 + sr) * K + shf;
  unsigned short* sa = As + sr * LDT + shf;
  unsigned short* sb = Bs + sr * LDT + shf;

  const int arow = wr * 64 + (lane & 15);
  const int brow = wc * 64 + (lane & 15);
  const int kf   = (lane >> 4) * 8;

  for (int k0 = 0; k0 < K; k0 += 32) {
    __syncthreads();   // prior iteration's ds_reads drained before overwrite
    *(u16x8*)(sa)     = *(const u16x8*)(Ag + k0);
    *(u16x8*)(sa + 8) = *(const u16x8*)(Ag + k0 + 8);
    *(u16x8*)(sb)     = *(const u16x8*)(Bg + k0);
    *(u16x8*)(sb + 8) = *(const u16x8*)(Bg + k0 + 8);
    __syncthreads();

    bf16x8 af[4], bf[4];
#pragma unroll
    for (int i = 0; i < 4; i++) {
      af[i] = __builtin_bit_cast(bf16x8, *(const u16x8*)(As + (arow + i*16)*LDT + kf));
      bf[i] = __builtin_bit_cast(bf16x8, *(const u16x8*)(Bs + (brow + i*16)*LDT + kf));
    }
#pragma unroll
    for (int mi = 0; mi < 4; mi++)
#pragma unroll
      for (int ni = 0; ni < 4; ni++)
        acc[mi][ni] = __builtin_amdgcn_mfma_f32_16x16x32_bf16(af[mi], bf[ni], acc[mi][ni], 0, 0, 0);
  }

#pragma unroll
  for (int ni = 0; ni < 4; ni++) {
    const int col = n0 + wc * 64 + ni * 16 + (lane & 15);
    const float bv = bias ? bias[col] : 0.0f;
#pragma unroll
    for (int mi = 0; mi < 4; mi++) {
      const int rb = m0 + wr * 64 + mi * 16 + (lane >> 4) * 4;
#pragma unroll
      for (int r = 0; r < 4; r++) {
        float v = (acc[mi][ni][r] + bv) * alpha;
        if (OUT_BF16) Cb[(size_t)(rb + r) * N + col] = f32_to_bf16(v);
        else          Cf[(size_t)(rb + r) * N + col] = v;
      }
    }
  }
}

// ---- row softmax: scores fp32 [2048][2048] -> P bf16 ----
__global__ __launch_bounds__(256) void softmax_kernel(
    const float* __restrict__ S, unsigned short* __restrict__ P) {
  const int row = blockIdx.x;
  const float* sp = S + (size_t)row * SD;
  const int tid = threadIdx.x, lane = tid & 63, w = tid >> 6;
  float4 v0 = *(const float4*)(sp + tid * 8);
  float4 v1 = *(const float4*)(sp + tid * 8 + 4);
  float x[8] = {v0.x,v0.y,v0.z,v0.w,v1.x,v1.y,v1.z,v1.w};
  float m = x[0];
#pragma unroll
  for (int j = 1; j < 8; j++) m = fmaxf(m, x[j]);
#pragma unroll
  for (int off = 32; off >= 1; off >>= 1) m = fmaxf(m, __shfl_xor(m, off));
  __shared__ float redm[4];
  if (lane == 0) redm[w] = m;
  __syncthreads();
  m = fmaxf(fmaxf(redm[0], redm[1]), fmaxf(redm[2], redm[3]));
  float e[8]; float s = 0.0f;
#pragma unroll
  for (int j = 0; j < 8; j++) { e[j] = __expf(x[j] - m); s += e[j]; }
#pragma unroll
  for (int off = 32; off >= 1; off >>= 1) s += __shfl_xor(s, off);
  __shared__ float reds[4];
  if (lane == 0) reds[w] = s;
  __syncthreads();
  s = reds[0] + reds[1] + reds[2] + reds[3];
  const float inv = 1.0f / s;
  u16x8 o;
#pragma unroll
  for (int j = 0; j < 8; j++) o[j] = f32_to_bf16(e[j] * inv);
  *(u16x8*)(P + (size_t)row * SD + tid * 8) = o;
}

// ---- launch: per-batch pipeline, ~50 MB workspace total ----
extern "C" void kernel_launch(void* const* d_in, const int* in_sizes, int n_in,
                              void* d_out, int out_size, void* d_ws, size_t ws_size,
                              hipStream_t stream) {
  const float* x  = (const float*)d_in[0];
  const float* Wq = (const float*)d_in[1];
  const float* bq = (const float*)d_in[2];
  const float* Wk = (const float*)d_in[3];
  const float* bk = (const float*)d_in[4];
  const float* Wv = (const float*)d_in[5];
  const float* bv = (const float*)d_in[6];
  float* out = (float*)d_out;                      // fp32 output (ref dtype)
  char* ws = (char*)d_ws;

  // workspace layout (bytes), total 52,428,800 (50 MB)
  unsigned short* wt     = (unsigned short*)(ws + 0);         // 3 x [1024][1024] bf16, 6 MB
  unsigned short* xb     = (unsigned short*)(ws + 6291456);   // [2048][1024] bf16, 4 MB
  unsigned short* Qb     = (unsigned short*)(ws + 10485760);  // 4 MB
  unsigned short* Kb     = (unsigned short*)(ws + 14680064);  // 4 MB
  unsigned short* Vb     = (unsigned short*)(ws + 18874368);  // 4 MB
  unsigned short* Vt     = (unsigned short*)(ws + 23068672);  // [1024][2048] bf16, 4 MB
  float*          scores = (float*)         (ws + 27262976);  // [2048][2048] fp32, 16 MB
  unsigned short* P      = (unsigned short*)(ws + 44040192);  // [2048][2048] bf16, 8 MB

  transpose_w_kernel<<<dim3(32, 32, 3), dim3(32, 8), 0, stream>>>(Wq, Wk, Wv, wt);

  const float scale = 0.03125f;  // 1/sqrt(1024)
  for (int b = 0; b < BD; b++) {
    const float* xbatch = x + (size_t)b * SD * HD;
    float* outb = out + (size_t)b * SD * HD;

    cast_x_kernel<<<SD * HD / 8 / 256, 256, 0, stream>>>(xbatch, xb);

    // projections: Q/K/V = xb @ W + b   (M=2048, N=1024, K=1024)
    gemm_bt_kernel<1><<<dim3(HD/128, SD/128), 256, 0, stream>>>(
        xb, wt + 0*1048576, bq, nullptr, Qb, SD, HD, HD, 1.0f);
    gemm_bt_kernel<1><<<dim3(HD/128, SD/128), 256, 0, stream>>>(
        xb, wt + 1*1048576, bk, nullptr, Kb, SD, HD, HD, 1.0f);
    gemm_bt_kernel<1><<<dim3(HD/128, SD/128), 256, 0, stream>>>(
        xb, wt + 2*1048576, bv, nullptr, Vb, SD, HD, HD, 1.0f);

    transpose_v_kernel<<<dim3(HD/32, SD/32), dim3(32, 8), 0, stream>>>(Vb, Vt);

    // scores[q][k] = scale * Q.K^T  (fp32, M=N=2048, K=1024)
    gemm_bt_kernel<0><<<dim3(SD/128, SD/128), 256, 0, stream>>>(
        Qb, Kb, nullptr, scores, nullptr, SD, SD, HD, scale);

    softmax_kernel<<<SD, 256, 0, stream>>>(scores, P);

    // out[q][h] = P.Vt^T  fp32 out  (M=2048, N=1024, K=2048)
    gemm_bt_kernel<0><<<dim3(HD/128, SD/128), 256, 0, stream>>>(
        P, Vt, nullptr, outb, nullptr, SD, HD, SD, 1.0f);
  }
}

// Round 5
// 453.468 us; speedup vs baseline: 2.9301x; 2.9301x over previous
//
#include <hip/hip_runtime.h>
#include <stdint.h>

// B=8, S=2048, H=1024. fp32 in, fp32 out. bf16 MFMA compute core.
#define BD 8
#define SD 2048
#define HD 1024

typedef __bf16 bf16x8 __attribute__((ext_vector_type(8)));
typedef float f32x4 __attribute__((ext_vector_type(4)));
typedef unsigned short u16x8 __attribute__((ext_vector_type(8)));

typedef const __attribute__((address_space(1))) void* gas_ptr;
typedef __attribute__((address_space(3))) void* las_ptr;

__device__ __forceinline__ void gload16(const void* g, void* l) {
  // direct global->LDS DMA, 16B/lane; LDS dest = wave-uniform base + lane*16
  __builtin_amdgcn_global_load_lds((gas_ptr)g, (las_ptr)l, 16, 0, 0);
}

__device__ __forceinline__ unsigned short f32_to_bf16(float f) {
  union { float f; unsigned u; } v; v.f = f;
  unsigned u = v.u;
  return (unsigned short)((u + 0x7FFFu + ((u >> 16) & 1u)) >> 16);  // RNE
}

// ---- cast x: fp32 -> bf16 ----
__global__ __launch_bounds__(256) void cast_x_kernel(
    const float* __restrict__ x, unsigned short* __restrict__ xb) {
  size_t i = (size_t)blockIdx.x * 256 + threadIdx.x;   // grid sized exactly
  const float4* xp = (const float4*)x;
  float4 a = xp[2*i], b = xp[2*i + 1];
  float v[8] = {a.x,a.y,a.z,a.w,b.x,b.y,b.z,b.w};
  u16x8 o;
#pragma unroll
  for (int j = 0; j < 8; j++) o[j] = f32_to_bf16(v[j]);
  *(u16x8*)(xb + i*8) = o;
}

// ---- W [K][N] fp32 -> W^T bf16 [N][K], 3 weights via blockIdx.z ----
__global__ __launch_bounds__(256) void transpose_w_kernel(
    const float* __restrict__ Wq, const float* __restrict__ Wk,
    const float* __restrict__ Wv, unsigned short* __restrict__ wt) {
  __shared__ float tile[32][33];
  const int w = blockIdx.z;
  const float* W = (w == 0) ? Wq : ((w == 1) ? Wk : Wv);
  const int n0 = blockIdx.x * 32, k0 = blockIdx.y * 32;
  const int x = threadIdx.x, y = threadIdx.y;       // block (32,8)
  for (int j = 0; j < 32; j += 8)
    tile[y + j][x] = W[(size_t)(k0 + y + j) * HD + n0 + x];
  __syncthreads();
  unsigned short* dst = wt + (size_t)w * HD * HD;
  for (int j = 0; j < 32; j += 8)
    dst[(size_t)(n0 + y + j) * HD + k0 + x] = f32_to_bf16(tile[x][y + j]);
}

// ---- V [z][2048][1024] bf16 -> Vt [z][1024][2048] bf16 ----
__global__ __launch_bounds__(256) void transpose_v_kernel(
    const unsigned short* __restrict__ V, unsigned short* __restrict__ Vt) {
  __shared__ unsigned short tile[32][33];
  const unsigned short* Vz = V + (size_t)blockIdx.z * SD * HD;
  unsigned short* Vtz = Vt + (size_t)blockIdx.z * HD * SD;
  const int h0 = blockIdx.x * 32, s0 = blockIdx.y * 32;
  const int x = threadIdx.x, y = threadIdx.y;       // block (32,8)
  for (int j = 0; j < 32; j += 8)
    tile[y + j][x] = Vz[(size_t)(s0 + y + j) * HD + h0 + x];
  __syncthreads();
  for (int j = 0; j < 32; j += 8)
    Vtz[(size_t)(h0 + y + j) * SD + s0 + x] = tile[x][y + j];
}

// ---- GEMM: C_z[M][N] = alpha * (A_z[M][K] * Bt_z[N][K]^T + bias_z[n]) ----
// m97 structure: 128x128 tile, BK=32, global_load_lds width=16, linear LDS
// with k-slot XOR swizzle slot^=((row>>1)&3) (both-sides: pre-swizzled global
// source + swizzled ds_read; rule #21). Bank math: 64B rows, 16B slots; the
// (row>>1) XOR spreads an 8-lane clock group across all 32 banks exactly once.
// 4 waves (2x2), 4x4 frags of 16x16x32 bf16 MFMA each.
template<int OUT_BF16>
__global__ __launch_bounds__(256, 2) void gemm_bt_lds(
    const unsigned short* __restrict__ A, size_t sA,
    const unsigned short* __restrict__ Bt, size_t sB,
    const float* __restrict__ b0, const float* __restrict__ b1,
    const float* __restrict__ b2,
    float* __restrict__ Cf, unsigned short* __restrict__ Cb, size_t sC,
    int M, int N, int K, float alpha)
{
  __shared__ unsigned short As[128 * 32];   // linear [row][32] ushorts, 8 KB
  __shared__ unsigned short Bs[128 * 32];
  const int z = blockIdx.z;
  A  += (size_t)z * sA;
  Bt += (size_t)z * sB;
  const float* bias = (z == 0) ? b0 : ((z == 1) ? b1 : b2);
  const int tid = threadIdx.x, lane = tid & 63, w = tid >> 6;
  const int wr = w >> 1, wc = w & 1;
  const int m0 = blockIdx.y * 128, n0 = blockIdx.x * 128;

  f32x4 acc[4][4] = {};

  // staging: wave w stages chunks j0=2w, j1=2w+1 (each 512 ushorts = 16 rows).
  // lane covers physical slot (lane&3) of row j*16 + (lane>>2); the DATA for
  // physical slot p of row r is logical k-slot p^((r>>1)&3)  (XOR swizzle).
  const int j0 = 2 * w, j1 = j0 + 1;
  const int r0 = j0 * 16 + (lane >> 2), r1 = j1 * 16 + (lane >> 2);
  const int c0 = (((lane & 3) ^ ((r0 >> 1) & 3)) * 8);
  const int c1 = (((lane & 3) ^ ((r1 >> 1) & 3)) * 8);
  const unsigned short* Ag0 = A  + (size_t)(m0 + r0) * K + c0;
  const unsigned short* Ag1 = A  + (size_t)(m0 + r1) * K + c1;
  const unsigned short* Bg0 = Bt + (size_t)(n0 + r0) * K + c0;
  const unsigned short* Bg1 = Bt + (size_t)(n0 + r1) * K + c1;
  unsigned short* la0 = As + j0 * 512;   // wave-uniform LDS bases
  unsigned short* la1 = As + j1 * 512;
  unsigned short* lb0 = Bs + j0 * 512;
  unsigned short* lb1 = Bs + j1 * 512;

  const int ar = wr * 64 + (lane & 15);   // logical A row within tile
  const int br = wc * 64 + (lane & 15);
  const int q  = lane >> 4;               // logical k-slot of this lane's frag

  for (int k0 = 0; k0 < K; k0 += 32) {
    __syncthreads();                      // drain prior ds_reads
    gload16(Ag0 + k0, la0);
    gload16(Ag1 + k0, la1);
    gload16(Bg0 + k0, lb0);
    gload16(Bg1 + k0, lb1);
    __syncthreads();                      // vmcnt(0) drain -> LDS visible

    bf16x8 af[4], bf[4];
#pragma unroll
    for (int i = 0; i < 4; i++) {
      const int ra = ar + i * 16, rb = br + i * 16;
      af[i] = __builtin_bit_cast(bf16x8,
          *(const u16x8*)(As + ra * 32 + ((q ^ ((ra >> 1) & 3)) * 8)));
      bf[i] = __builtin_bit_cast(bf16x8,
          *(const u16x8*)(Bs + rb * 32 + ((q ^ ((rb >> 1) & 3)) * 8)));
    }
#pragma unroll
    for (int mi = 0; mi < 4; mi++)
#pragma unroll
      for (int ni = 0; ni < 4; ni++)
        acc[mi][ni] = __builtin_amdgcn_mfma_f32_16x16x32_bf16(
            af[mi], bf[ni], acc[mi][ni], 0, 0, 0);
  }

  float* Cfz = Cf ? Cf + (size_t)z * sC : nullptr;
  unsigned short* Cbz = Cb ? Cb + (size_t)z * sC : nullptr;
#pragma unroll
  for (int ni = 0; ni < 4; ni++) {
    const int col = n0 + wc * 64 + ni * 16 + (lane & 15);
    const float bv = bias ? bias[col] : 0.0f;
#pragma unroll
    for (int mi = 0; mi < 4; mi++) {
      const int rb = m0 + wr * 64 + mi * 16 + (lane >> 4) * 4;
#pragma unroll
      for (int r = 0; r < 4; r++) {
        float v = (acc[mi][ni][r] + bv) * alpha;
        if (OUT_BF16) Cbz[(size_t)(rb + r) * N + col] = f32_to_bf16(v);
        else          Cfz[(size_t)(rb + r) * N + col] = v;
      }
    }
  }
}

// ---- row softmax: S fp32 [rows][2048] -> P bf16 [rows][2048] ----
__global__ __launch_bounds__(256) void softmax_kernel(
    const float* __restrict__ S, unsigned short* __restrict__ P) {
  const int row = blockIdx.x;
  const float* sp = S + (size_t)row * SD;
  const int tid = threadIdx.x, lane = tid & 63, w = tid >> 6;
  float4 v0 = *(const float4*)(sp + tid * 8);
  float4 v1 = *(const float4*)(sp + tid * 8 + 4);
  float x[8] = {v0.x,v0.y,v0.z,v0.w,v1.x,v1.y,v1.z,v1.w};
  float m = x[0];
#pragma unroll
  for (int j = 1; j < 8; j++) m = fmaxf(m, x[j]);
#pragma unroll
  for (int off = 32; off >= 1; off >>= 1) m = fmaxf(m, __shfl_xor(m, off));
  __shared__ float redm[4];
  if (lane == 0) redm[w] = m;
  __syncthreads();
  m = fmaxf(fmaxf(redm[0], redm[1]), fmaxf(redm[2], redm[3]));
  float e[8]; float s = 0.0f;
#pragma unroll
  for (int j = 0; j < 8; j++) { e[j] = __expf(x[j] - m); s += e[j]; }
#pragma unroll
  for (int off = 32; off >= 1; off >>= 1) s += __shfl_xor(s, off);
  __shared__ float reds[4];
  if (lane == 0) reds[w] = s;
  __syncthreads();
  s = reds[0] + reds[1] + reds[2] + reds[3];
  const float inv = 1.0f / s;
  u16x8 o;
#pragma unroll
  for (int j = 0; j < 8; j++) o[j] = f32_to_bf16(e[j] * inv);
  *(u16x8*)(P + (size_t)row * SD + tid * 8) = o;
}

// ---- launch ----
extern "C" void kernel_launch(void* const* d_in, const int* in_sizes, int n_in,
                              void* d_out, int out_size, void* d_ws, size_t ws_size,
                              hipStream_t stream) {
  const float* x  = (const float*)d_in[0];
  const float* Wq = (const float*)d_in[1];
  const float* bq = (const float*)d_in[2];
  const float* Wk = (const float*)d_in[3];
  const float* bk = (const float*)d_in[4];
  const float* Wv = (const float*)d_in[5];
  const float* bv = (const float*)d_in[6];
  float* out = (float*)d_out;
  char* ws = (char*)d_ws;
  const size_t MB = 1024 * 1024;
  const float scale = 0.03125f;  // 1/sqrt(1024)
  const size_t BH = (size_t)SD * HD;   // 2M elems per batch (Q/K/V)
  const size_t SS = (size_t)SD * SD;   // 4M elems per batch (scores/P)

  if (ws_size >= 198 * MB) {
    // tier1: fully batched. wt 0-6 | Q 6-38 | K 38-70 | V 70-102 (scores pair
    // in phase B) | Vt 102-134 | P(all 8) 134-198 (xb overlaps 134-166 phase A)
    unsigned short* wt = (unsigned short*)(ws + 0);
    unsigned short* Qb = (unsigned short*)(ws + 6 * MB);
    unsigned short* Kb = (unsigned short*)(ws + 38 * MB);
    unsigned short* Vb = (unsigned short*)(ws + 70 * MB);
    unsigned short* Vt = (unsigned short*)(ws + 102 * MB);
    unsigned short* P  = (unsigned short*)(ws + 134 * MB);
    unsigned short* xb = (unsigned short*)(ws + 134 * MB);
    float* scores      = (float*)(ws + 70 * MB);

    transpose_w_kernel<<<dim3(32, 32, 3), dim3(32, 8), 0, stream>>>(Wq, Wk, Wv, wt);
    cast_x_kernel<<<8192, 256, 0, stream>>>(x, xb);
    // fused QKV projection: z=weight, M=16384
    gemm_bt_lds<1><<<dim3(HD/128, (BD*SD)/128, 3), 256, 0, stream>>>(
        xb, 0, wt, (size_t)HD*HD, bq, bk, bv,
        nullptr, Qb, (size_t)32*MB/2, BD*SD, HD, HD, 1.0f);
    transpose_v_kernel<<<dim3(HD/32, SD/32, BD), dim3(32, 8), 0, stream>>>(Vb, Vt);
    for (int p = 0; p < 4; p++) {
      gemm_bt_lds<0><<<dim3(SD/128, SD/128, 2), 256, 0, stream>>>(
          Qb + (size_t)p*2*BH, BH, Kb + (size_t)p*2*BH, BH,
          nullptr, nullptr, nullptr, scores, nullptr, SS, SD, SD, HD, scale);
      softmax_kernel<<<2*SD, 256, 0, stream>>>(scores, P + (size_t)p*2*SS);
    }
    gemm_bt_lds<0><<<dim3(HD/128, SD/128, BD), 256, 0, stream>>>(
        P, SS, Vt, BH, nullptr, nullptr, nullptr,
        out, nullptr, BH, SD, HD, SD, 1.0f);
  } else if (ws_size >= 166 * MB) {
    // tier2: as tier1 but P per-pair (16 MB at 134), PV inside pair loop
    unsigned short* wt = (unsigned short*)(ws + 0);
    unsigned short* Qb = (unsigned short*)(ws + 6 * MB);
    unsigned short* Kb = (unsigned short*)(ws + 38 * MB);
    unsigned short* Vb = (unsigned short*)(ws + 70 * MB);
    unsigned short* Vt = (unsigned short*)(ws + 102 * MB);
    unsigned short* P  = (unsigned short*)(ws + 134 * MB);
    unsigned short* xb = (unsigned short*)(ws + 134 * MB);
    float* scores      = (float*)(ws + 70 * MB);

    transpose_w_kernel<<<dim3(32, 32, 3), dim3(32, 8), 0, stream>>>(Wq, Wk, Wv, wt);
    cast_x_kernel<<<8192, 256, 0, stream>>>(x, xb);
    gemm_bt_lds<1><<<dim3(HD/128, (BD*SD)/128, 3), 256, 0, stream>>>(
        xb, 0, wt, (size_t)HD*HD, bq, bk, bv,
        nullptr, Qb, (size_t)32*MB/2, BD*SD, HD, HD, 1.0f);
    transpose_v_kernel<<<dim3(HD/32, SD/32, BD), dim3(32, 8), 0, stream>>>(Vb, Vt);
    for (int p = 0; p < 4; p++) {
      gemm_bt_lds<0><<<dim3(SD/128, SD/128, 2), 256, 0, stream>>>(
          Qb + (size_t)p*2*BH, BH, Kb + (size_t)p*2*BH, BH,
          nullptr, nullptr, nullptr, scores, nullptr, SS, SD, SD, HD, scale);
      softmax_kernel<<<2*SD, 256, 0, stream>>>(scores, P);
      gemm_bt_lds<0><<<dim3(HD/128, SD/128, 2), 256, 0, stream>>>(
          P, SS, Vt + (size_t)p*2*BH, BH, nullptr, nullptr, nullptr,
          out + (size_t)p*2*BH, nullptr, BH, SD, HD, SD, 1.0f);
    }
  } else {
    // tier3: per-batch, 50 MB (round-3 layout), new GEMM core
    unsigned short* wt     = (unsigned short*)(ws + 0);
    unsigned short* xb     = (unsigned short*)(ws + 6291456);
    unsigned short* Qb     = (unsigned short*)(ws + 10485760);
    unsigned short* Kb     = (unsigned short*)(ws + 14680064);
    unsigned short* Vb     = (unsigned short*)(ws + 18874368);
    unsigned short* Vt     = (unsigned short*)(ws + 23068672);
    float*          scores = (float*)         (ws + 27262976);
    unsigned short* P      = (unsigned short*)(ws + 44040192);

    transpose_w_kernel<<<dim3(32, 32, 3), dim3(32, 8), 0, stream>>>(Wq, Wk, Wv, wt);
    for (int b = 0; b < BD; b++) {
      const float* xbatch = x + (size_t)b * BH;
      float* outb = out + (size_t)b * BH;
      cast_x_kernel<<<1024, 256, 0, stream>>>(xbatch, xb);
      gemm_bt_lds<1><<<dim3(HD/128, SD/128, 3), 256, 0, stream>>>(
          xb, 0, wt, (size_t)HD*HD, bq, bk, bv,
          nullptr, Qb, (size_t)BH, SD, HD, HD, 1.0f);
      transpose_v_kernel<<<dim3(HD/32, SD/32, 1), dim3(32, 8), 0, stream>>>(Vb, Vt);
      gemm_bt_lds<0><<<dim3(SD/128, SD/128, 1), 256, 0, stream>>>(
          Qb, 0, Kb, 0, nullptr, nullptr, nullptr,
          scores, nullptr, 0, SD, SD, HD, scale);
      softmax_kernel<<<SD, 256, 0, stream>>>(scores, P);
      gemm_bt_lds<0><<<dim3(HD/128, SD/128, 1), 256, 0, stream>>>(
          P, 0, Vt, 0, nullptr, nullptr, nullptr,
          outb, nullptr, 0, SD, HD, SD, 1.0f);
    }
  }
}

// Round 6
// 446.015 us; speedup vs baseline: 2.9790x; 1.0167x over previous
//
#include <hip/hip_runtime.h>
#include <stdint.h>

// B=8, S=2048, H=1024. fp32 in, fp32 out. bf16 MFMA compute core.
#define BD 8
#define SD 2048
#define HD 1024

typedef __bf16 bf16x8 __attribute__((ext_vector_type(8)));
typedef float f32x4 __attribute__((ext_vector_type(4)));
typedef unsigned short u16x8 __attribute__((ext_vector_type(8)));

typedef const __attribute__((address_space(1))) void* gas_ptr;
typedef __attribute__((address_space(3))) void* las_ptr;

__device__ __forceinline__ void gload16(const void* g, void* l) {
  __builtin_amdgcn_global_load_lds((gas_ptr)g, (las_ptr)l, 16, 0, 0);
}

__device__ __forceinline__ unsigned short f32_to_bf16(float f) {
  union { float f; unsigned u; } v; v.f = f;
  unsigned u = v.u;
  return (unsigned short)((u + 0x7FFFu + ((u >> 16) & 1u)) >> 16);  // RNE
}

// ---- cast x: fp32 -> bf16 ----
__global__ __launch_bounds__(256) void cast_x_kernel(
    const float* __restrict__ x, unsigned short* __restrict__ xb) {
  size_t i = (size_t)blockIdx.x * 256 + threadIdx.x;
  const float4* xp = (const float4*)x;
  float4 a = xp[2*i], b = xp[2*i + 1];
  float v[8] = {a.x,a.y,a.z,a.w,b.x,b.y,b.z,b.w};
  u16x8 o;
#pragma unroll
  for (int j = 0; j < 8; j++) o[j] = f32_to_bf16(v[j]);
  *(u16x8*)(xb + i*8) = o;
}

// ---- W [K][N] fp32 -> W^T bf16 [N][K], 3 weights via blockIdx.z ----
__global__ __launch_bounds__(256) void transpose_w_kernel(
    const float* __restrict__ Wq, const float* __restrict__ Wk,
    const float* __restrict__ Wv, unsigned short* __restrict__ wt) {
  __shared__ float tile[32][33];
  const int w = blockIdx.z;
  const float* W = (w == 0) ? Wq : ((w == 1) ? Wk : Wv);
  const int n0 = blockIdx.x * 32, k0 = blockIdx.y * 32;
  const int x = threadIdx.x, y = threadIdx.y;       // block (32,8)
  for (int j = 0; j < 32; j += 8)
    tile[y + j][x] = W[(size_t)(k0 + y + j) * HD + n0 + x];
  __syncthreads();
  unsigned short* dst = wt + (size_t)w * HD * HD;
  for (int j = 0; j < 32; j += 8)
    dst[(size_t)(n0 + y + j) * HD + k0 + x] = f32_to_bf16(tile[x][y + j]);
}

// ---- V [z][2048][1024] bf16 -> Vt [z][1024][2048] bf16 ----
__global__ __launch_bounds__(256) void transpose_v_kernel(
    const unsigned short* __restrict__ V, unsigned short* __restrict__ Vt) {
  __shared__ unsigned short tile[32][33];
  const unsigned short* Vz = V + (size_t)blockIdx.z * SD * HD;
  unsigned short* Vtz = Vt + (size_t)blockIdx.z * HD * SD;
  const int h0 = blockIdx.x * 32, s0 = blockIdx.y * 32;
  const int x = threadIdx.x, y = threadIdx.y;       // block (32,8)
  for (int j = 0; j < 32; j += 8)
    tile[y + j][x] = Vz[(size_t)(s0 + y + j) * HD + h0 + x];
  __syncthreads();
  for (int j = 0; j < 32; j += 8)
    Vtz[(size_t)(h0 + y + j) * SD + s0 + x] = tile[x][y + j];
}

// ---- 256x256 8-phase GEMM: C_z = alpha*(A_z[M][K] * Bt_z[N][K]^T + bias_z) ----
// 8 waves (2Mx4N), BK=64, double-buffered 128KiB LDS, counted vmcnt(6),
// st_16x32-class XOR swizzle (both sides), bijective XCD blockIdx swizzle.
// Staging order per tile: B0,B1,A0,A1. Per 4-phase group computing tile t:
//   ph0: ds_read all b + a[0-3]; stage (t+1)A1;  MFMA m0-3 x n0-1
//   ph1: ds_read a[4-7];         stage (t+2)B0;  MFMA m0-3 x n2-3
//   ph2:                         stage (t+2)B1;  MFMA m4-7 x n0-1
//   ph3:                         stage (t+2)A0;  MFMA m4-7 x n2-3; vmcnt(6)
// Reads of each LDS region complete >=1 barrier before its overwrite;
// vmcnt(6) at each group end == 3 half-tiles in flight (exactly periodic).
template<int OUT_BF16>
__global__ __launch_bounds__(512, 2) void gemm256(
    const unsigned short* __restrict__ A, size_t sA,
    const unsigned short* __restrict__ Bt, size_t sB,
    const float* __restrict__ b0, const float* __restrict__ b1,
    const float* __restrict__ b2,
    float* __restrict__ Cf, unsigned short* __restrict__ Cb, size_t sC,
    int M, int N, int K, float alpha)
{
  __shared__ unsigned short As[2 * 256 * 64];   // 64 KB
  __shared__ unsigned short Bs[2 * 256 * 64];   // 64 KB

  // bijective XCD swizzle over flattened grid (all grids % 8 == 0)
  const int gx = gridDim.x, gy = gridDim.y;
  const int nwg = gx * gy * gridDim.z;
  const int flat = blockIdx.x + gx * (blockIdx.y + gy * blockIdx.z);
  const int swz = (flat & 7) * (nwg >> 3) + (flat >> 3);
  const int tz = swz / (gx * gy);
  const int rem = swz - tz * gx * gy;
  const int ty = rem / gx, tx = rem - (rem / gx) * gx;
  const int m0 = ty * 256, n0 = tx * 256;

  A  += (size_t)tz * sA;
  Bt += (size_t)tz * sB;
  const float* bias = (tz == 0) ? b0 : ((tz == 1) ? b1 : b2);

  const int tid = threadIdx.x, lane = tid & 63, w = tid >> 6;  // 8 waves
  const int wr = w >> 2, wc = w & 3;          // 2 x 4 wave grid
  const int nt = K >> 6;                      // BK=64 tiles (nt >= 3 here)

  // staging lane constants: lane covers row (base + lane>>3), 16B slot lane&7;
  // source slot pre-swizzled: s ^= ((row>>2)&1)<<1, row bit2 = lane bit5.
  const int lrow = lane >> 3;
  const int sslot8 = (((lane & 7) ^ (((lane >> 5) & 1) << 1)) << 3);

  // ds_read lane constants: frag row = base16 + (lane&15) -> row bit2 = lane bit2
  const int rA = wr * 128 + (lane & 15);
  const int rB = wc * 64 + (lane & 15);
  const int qq = lane >> 4;
  const int sxor = ((lane >> 2) & 1) << 1;

#define STAGE_A(t,h) do { \
    const unsigned short* _g = A + (size_t)(m0 + (h)*128 + w*16 + lrow) * K + (size_t)((t)*64 + sslot8); \
    unsigned short* _l = &As[((((t)&1)*256 + (h)*128 + w*16)) * 64]; \
    gload16(_g, _l); gload16(_g + (size_t)8*K, _l + 512); } while(0)
#define STAGE_B(t,h) do { \
    const unsigned short* _g = Bt + (size_t)(n0 + (h)*128 + w*16 + lrow) * K + (size_t)((t)*64 + sslot8); \
    unsigned short* _l = &Bs[((((t)&1)*256 + (h)*128 + w*16)) * 64]; \
    gload16(_g, _l); gload16(_g + (size_t)8*K, _l + 512); } while(0)
#define LDA(buf,m,ks) __builtin_bit_cast(bf16x8, *(const u16x8*)(&As[(buf)*16384 + (rA + (m)*16)*64 + ((((ks)*4 + qq) ^ sxor) << 3)]))
#define LDB(buf,n,ks) __builtin_bit_cast(bf16x8, *(const u16x8*)(&Bs[(buf)*16384 + (rB + (n)*16)*64 + ((((ks)*4 + qq) ^ sxor) << 3)]))
#define MFMA_Q(AV,MBASE,NLO) \
    _Pragma("unroll") for (int _m = 0; _m < 4; _m++) \
    _Pragma("unroll") for (int _n = 0; _n < 2; _n++) \
    _Pragma("unroll") for (int _k = 0; _k < 2; _k++) \
      acc[(MBASE)+_m][(NLO)+_n] = __builtin_amdgcn_mfma_f32_16x16x32_bf16( \
          AV[_m][_k], bv[(NLO)+_n][_k], acc[(MBASE)+_m][(NLO)+_n], 0, 0, 0);

  f32x4 acc[8][4] = {};
  bf16x8 av0[4][2], av1[4][2], bv[4][2];

  // prologue: tile0 (B0,B1,A0,A1) + tile1 (B0,B1,A0) = 14 loads/wave
  STAGE_B(0,0); STAGE_B(0,1); STAGE_A(0,0); STAGE_A(0,1);
  STAGE_B(1,0); STAGE_B(1,1); STAGE_A(1,0);
  asm volatile("s_waitcnt vmcnt(6)" ::: "memory");   // tile0 fully landed
  __builtin_amdgcn_s_barrier();

  for (int t = 0; t < nt; ++t) {
    const int cur = t & 1;
    // ---- phase 0
#pragma unroll
    for (int n = 0; n < 4; n++) { bv[n][0] = LDB(cur,n,0); bv[n][1] = LDB(cur,n,1); }
#pragma unroll
    for (int m = 0; m < 4; m++) { av0[m][0] = LDA(cur,m,0); av0[m][1] = LDA(cur,m,1); }
    if (t + 1 < nt) STAGE_A(t+1, 1);
    __builtin_amdgcn_s_barrier();
    __builtin_amdgcn_s_setprio(1);
    MFMA_Q(av0, 0, 0);
    __builtin_amdgcn_s_setprio(0);
    __builtin_amdgcn_s_barrier();
    // ---- phase 1
#pragma unroll
    for (int m = 0; m < 4; m++) { av1[m][0] = LDA(cur,m+4,0); av1[m][1] = LDA(cur,m+4,1); }
    if (t + 2 < nt) STAGE_B(t+2, 0);
    __builtin_amdgcn_s_barrier();
    __builtin_amdgcn_s_setprio(1);
    MFMA_Q(av0, 0, 2);
    __builtin_amdgcn_s_setprio(0);
    __builtin_amdgcn_s_barrier();
    // ---- phase 2
    if (t + 2 < nt) STAGE_B(t+2, 1);
    __builtin_amdgcn_s_barrier();
    __builtin_amdgcn_s_setprio(1);
    MFMA_Q(av1, 4, 0);
    __builtin_amdgcn_s_setprio(0);
    __builtin_amdgcn_s_barrier();
    // ---- phase 3
    if (t + 2 < nt) STAGE_A(t+2, 0);
    __builtin_amdgcn_s_barrier();
    __builtin_amdgcn_s_setprio(1);
    MFMA_Q(av1, 4, 2);
    __builtin_amdgcn_s_setprio(0);
    if (t < nt - 2) asm volatile("s_waitcnt vmcnt(6)" ::: "memory");
    else            asm volatile("s_waitcnt vmcnt(0)" ::: "memory");
    __builtin_amdgcn_s_barrier();
  }

  float* Cfz = Cf ? Cf + (size_t)tz * sC : nullptr;
  unsigned short* Cbz = Cb ? Cb + (size_t)tz * sC : nullptr;
#pragma unroll
  for (int n = 0; n < 4; n++) {
    const int col = n0 + wc * 64 + n * 16 + (lane & 15);
    const float bvv = bias ? bias[col] : 0.0f;
#pragma unroll
    for (int m = 0; m < 8; m++) {
      const int row = m0 + wr * 128 + m * 16 + (lane >> 4) * 4;
#pragma unroll
      for (int r = 0; r < 4; r++) {
        float v = (acc[m][n][r] + bvv) * alpha;
        if (OUT_BF16) Cbz[(size_t)(row + r) * N + col] = f32_to_bf16(v);
        else          Cfz[(size_t)(row + r) * N + col] = v;
      }
    }
  }
#undef STAGE_A
#undef STAGE_B
#undef LDA
#undef LDB
#undef MFMA_Q
}

// ---- row softmax: S fp32 [rows][2048] -> P bf16 [rows][2048] ----
__global__ __launch_bounds__(256) void softmax_kernel(
    const float* __restrict__ S, unsigned short* __restrict__ P) {
  const int row = blockIdx.x;
  const float* sp = S + (size_t)row * SD;
  const int tid = threadIdx.x, lane = tid & 63, w = tid >> 6;
  float4 v0 = *(const float4*)(sp + tid * 8);
  float4 v1 = *(const float4*)(sp + tid * 8 + 4);
  float x[8] = {v0.x,v0.y,v0.z,v0.w,v1.x,v1.y,v1.z,v1.w};
  float m = x[0];
#pragma unroll
  for (int j = 1; j < 8; j++) m = fmaxf(m, x[j]);
#pragma unroll
  for (int off = 32; off >= 1; off >>= 1) m = fmaxf(m, __shfl_xor(m, off));
  __shared__ float redm[4];
  if (lane == 0) redm[w] = m;
  __syncthreads();
  m = fmaxf(fmaxf(redm[0], redm[1]), fmaxf(redm[2], redm[3]));
  float e[8]; float s = 0.0f;
#pragma unroll
  for (int j = 0; j < 8; j++) { e[j] = __expf(x[j] - m); s += e[j]; }
#pragma unroll
  for (int off = 32; off >= 1; off >>= 1) s += __shfl_xor(s, off);
  __shared__ float reds[4];
  if (lane == 0) reds[w] = s;
  __syncthreads();
  s = reds[0] + reds[1] + reds[2] + reds[3];
  const float inv = 1.0f / s;
  u16x8 o;
#pragma unroll
  for (int j = 0; j < 8; j++) o[j] = f32_to_bf16(e[j] * inv);
  *(u16x8*)(P + (size_t)row * SD + tid * 8) = o;
}

// ---- launch ----
extern "C" void kernel_launch(void* const* d_in, const int* in_sizes, int n_in,
                              void* d_out, int out_size, void* d_ws, size_t ws_size,
                              hipStream_t stream) {
  const float* x  = (const float*)d_in[0];
  const float* Wq = (const float*)d_in[1];
  const float* bq = (const float*)d_in[2];
  const float* Wk = (const float*)d_in[3];
  const float* bk = (const float*)d_in[4];
  const float* Wv = (const float*)d_in[5];
  const float* bv = (const float*)d_in[6];
  float* out = (float*)d_out;
  char* ws = (char*)d_ws;
  const size_t MB = 1024 * 1024;
  const float scale = 0.03125f;              // 1/sqrt(1024)
  const size_t BH = (size_t)SD * HD;         // 2M elems (one batch of Q/K/V)
  const size_t SS = (size_t)SD * SD;         // 4M elems (one batch of scores/P)

  // layout: wt 0-6 | Qb 6-38 | Kb 38-70 | Vb 70-102 | xb 102-134 (->Vt after
  // proj) | scores fp32 134-(134+16G) | P bf16 over dead Vb at 70 (or @198 pv8)
  unsigned short* wt = (unsigned short*)(ws + 0);
  unsigned short* Qb = (unsigned short*)(ws + 6 * MB);
  unsigned short* Kb = (unsigned short*)(ws + 38 * MB);
  unsigned short* Vb = (unsigned short*)(ws + 70 * MB);
  unsigned short* xb = (unsigned short*)(ws + 102 * MB);
  unsigned short* Vt = (unsigned short*)(ws + 102 * MB);   // xb dead by then
  float* scores      = (float*)(ws + 134 * MB);

  int G; bool pv8;
  if      (ws_size >= 262 * MB) { G = 4; pv8 = true;  }
  else if (ws_size >= 198 * MB) { G = 4; pv8 = false; }
  else if (ws_size >= 166 * MB) { G = 2; pv8 = false; }
  else                          { G = 1; pv8 = false; }   // needs 150 MB
  unsigned short* P = (unsigned short*)(ws + (pv8 ? 198 * MB : 70 * MB));

  transpose_w_kernel<<<dim3(32, 32, 3), dim3(32, 8), 0, stream>>>(Wq, Wk, Wv, wt);
  cast_x_kernel<<<8192, 256, 0, stream>>>(x, xb);

  // fused QKV projection: z = weight index, M = 16384 (grid 4x64x3 = 768)
  gemm256<1><<<dim3(HD/256, (BD*SD)/256, 3), 512, 0, stream>>>(
      xb, 0, wt, (size_t)HD*HD, bq, bk, bv,
      nullptr, Qb, (size_t)16*MB, BD*SD, HD, HD, 1.0f);

  transpose_v_kernel<<<dim3(HD/32, SD/32, BD), dim3(32, 8), 0, stream>>>(Vb, Vt);

  const int ngroups = BD / G;
  for (int g = 0; g < ngroups; g++) {
    // scores = scale * Q K^T   (z = batch within group)
    gemm256<0><<<dim3(SD/256, SD/256, G), 512, 0, stream>>>(
        Qb + (size_t)g*G*BH, BH, Kb + (size_t)g*G*BH, BH,
        nullptr, nullptr, nullptr, scores, nullptr, SS, SD, SD, HD, scale);
    softmax_kernel<<<G*SD, 256, 0, stream>>>(
        scores, P + (pv8 ? (size_t)g*G*SS : 0));
    if (!pv8) {
      gemm256<0><<<dim3(HD/256, SD/256, G), 512, 0, stream>>>(
          P, SS, Vt + (size_t)g*G*BH, BH, nullptr, nullptr, nullptr,
          out + (size_t)g*G*BH, nullptr, BH, SD, HD, SD, 1.0f);
    }
  }
  if (pv8) {
    gemm256<0><<<dim3(HD/256, SD/256, BD), 512, 0, stream>>>(
        P, SS, Vt, BH, nullptr, nullptr, nullptr,
        out, nullptr, BH, SD, HD, SD, 1.0f);
  }
}

// Round 7
// 404.194 us; speedup vs baseline: 3.2873x; 1.1035x over previous
//
#include <hip/hip_runtime.h>
#include <stdint.h>

// B=8, S=2048, H=1024. fp32 in, fp32 out. bf16 MFMA compute core.
#define BD 8
#define SD 2048
#define HD 1024

typedef __bf16 bf16x8 __attribute__((ext_vector_type(8)));
typedef float f32x4 __attribute__((ext_vector_type(4)));
typedef unsigned short u16x8 __attribute__((ext_vector_type(8)));

typedef const __attribute__((address_space(1))) void* gas_ptr;
typedef __attribute__((address_space(3))) void* las_ptr;

__device__ __forceinline__ void gload16(const void* g, void* l) {
  __builtin_amdgcn_global_load_lds((gas_ptr)g, (las_ptr)l, 16, 0, 0);
}

__device__ __forceinline__ unsigned short f32_to_bf16(float f) {
  union { float f; unsigned u; } v; v.f = f;
  unsigned u = v.u;
  return (unsigned short)((u + 0x7FFFu + ((u >> 16) & 1u)) >> 16);  // RNE
}

// ---- cast x: fp32 -> bf16 ----
__global__ __launch_bounds__(256) void cast_x_kernel(
    const float* __restrict__ x, unsigned short* __restrict__ xb) {
  size_t i = (size_t)blockIdx.x * 256 + threadIdx.x;
  const float4* xp = (const float4*)x;
  float4 a = xp[2*i], b = xp[2*i + 1];
  float v[8] = {a.x,a.y,a.z,a.w,b.x,b.y,b.z,b.w};
  u16x8 o;
#pragma unroll
  for (int j = 0; j < 8; j++) o[j] = f32_to_bf16(v[j]);
  *(u16x8*)(xb + i*8) = o;
}

// ---- W [K][N] fp32 -> W^T bf16 [N][K], 3 weights via blockIdx.z ----
__global__ __launch_bounds__(256) void transpose_w_kernel(
    const float* __restrict__ Wq, const float* __restrict__ Wk,
    const float* __restrict__ Wv, unsigned short* __restrict__ wt) {
  __shared__ float tile[32][33];
  const int w = blockIdx.z;
  const float* W = (w == 0) ? Wq : ((w == 1) ? Wk : Wv);
  const int n0 = blockIdx.x * 32, k0 = blockIdx.y * 32;
  const int x = threadIdx.x, y = threadIdx.y;       // block (32,8)
  for (int j = 0; j < 32; j += 8)
    tile[y + j][x] = W[(size_t)(k0 + y + j) * HD + n0 + x];
  __syncthreads();
  unsigned short* dst = wt + (size_t)w * HD * HD;
  for (int j = 0; j < 32; j += 8)
    dst[(size_t)(n0 + y + j) * HD + k0 + x] = f32_to_bf16(tile[x][y + j]);
}

// ---- V [z][2048][1024] bf16 -> Vt [z][1024][2048] bf16 ----
__global__ __launch_bounds__(256) void transpose_v_kernel(
    const unsigned short* __restrict__ V, unsigned short* __restrict__ Vt) {
  __shared__ unsigned short tile[32][33];
  const unsigned short* Vz = V + (size_t)blockIdx.z * SD * HD;
  unsigned short* Vtz = Vt + (size_t)blockIdx.z * HD * SD;
  const int h0 = blockIdx.x * 32, s0 = blockIdx.y * 32;
  const int x = threadIdx.x, y = threadIdx.y;       // block (32,8)
  for (int j = 0; j < 32; j += 8)
    tile[y + j][x] = Vz[(size_t)(s0 + y + j) * HD + h0 + x];
  __syncthreads();
  for (int j = 0; j < 32; j += 8)
    Vtz[(size_t)(h0 + y + j) * SD + s0 + x] = tile[x][y + j];
}

// ---- 256x256 8-phase GEMM: C_z = alpha*(A_z[M][K] * Bt_z[N][K]^T + bias_z) ----
// 8 waves (2Mx4N), BK=64, double-buffered 128KiB LDS, counted vmcnt(6),
// full-row XOR swizzle: physical 16B-slot p of row r holds logical slot
// p^(r&7), applied BOTH sides (pre-swizzled global source + swizzled ds_read,
// rule #21). Bank math: 128B rows contribute nothing to bank index, so the
// (r&7) XOR must cover all 8 slots -> each 8-lane clock group of a
// ds_read_b128 hits all 32 banks exactly once (fixes round-6's 4-way, 9.4M).
// Staging order per tile: B0,B1,A0,A1. Per 4-phase group computing tile t:
//   ph0: ds_read all b + a[0-3]; stage (t+1)A1;  MFMA m0-3 x n0-1
//   ph1: ds_read a[4-7];         stage (t+2)B0;  MFMA m0-3 x n2-3
//   ph2:                         stage (t+2)B1;  MFMA m4-7 x n0-1
//   ph3:                         stage (t+2)A0;  MFMA m4-7 x n2-3; vmcnt(6)
template<int OUT_BF16>
__global__ __launch_bounds__(512, 2) void gemm256(
    const unsigned short* __restrict__ A, size_t sA,
    const unsigned short* __restrict__ Bt, size_t sB,
    const float* __restrict__ b0, const float* __restrict__ b1,
    const float* __restrict__ b2,
    float* __restrict__ Cf, unsigned short* __restrict__ Cb, size_t sC,
    int M, int N, int K, float alpha)
{
  __shared__ unsigned short As[2 * 256 * 64];   // 64 KB
  __shared__ unsigned short Bs[2 * 256 * 64];   // 64 KB

  // bijective XCD swizzle over flattened grid (all grids % 8 == 0)
  const int gx = gridDim.x, gy = gridDim.y;
  const int nwg = gx * gy * gridDim.z;
  const int flat = blockIdx.x + gx * (blockIdx.y + gy * blockIdx.z);
  const int swz = (flat & 7) * (nwg >> 3) + (flat >> 3);
  const int tz = swz / (gx * gy);
  const int rem = swz - tz * gx * gy;
  const int ty = rem / gx, tx = rem - (rem / gx) * gx;
  const int m0 = ty * 256, n0 = tx * 256;

  A  += (size_t)tz * sA;
  Bt += (size_t)tz * sB;
  const float* bias = (tz == 0) ? b0 : ((tz == 1) ? b1 : b2);

  const int tid = threadIdx.x, lane = tid & 63, w = tid >> 6;  // 8 waves
  const int wr = w >> 2, wc = w & 3;          // 2 x 4 wave grid
  const int nt = K >> 6;                      // BK=64 tiles (nt >= 3 here)

  // staging: lane covers row (base + lane>>3), physical 16B slot lane&7;
  // source logical slot = (lane&7) ^ (row&7) = (lane&7) ^ ((lane>>3)&7)
  // (all row bases are multiples of 8).
  const int lrow = lane >> 3;
  const int sslot8 = (((lane & 7) ^ ((lane >> 3) & 7)) << 3);

  // ds_read: frag row = base16 + (lane&15), bases multiple of 8 -> row&7 = lane&7
  const int rA = wr * 128 + (lane & 15);
  const int rB = wc * 64 + (lane & 15);
  const int qq = lane >> 4;
  const int sxor = lane & 7;

#define STAGE_A(t,h) do { \
    const unsigned short* _g = A + (size_t)(m0 + (h)*128 + w*16 + lrow) * K + (size_t)((t)*64 + sslot8); \
    unsigned short* _l = &As[((((t)&1)*256 + (h)*128 + w*16)) * 64]; \
    gload16(_g, _l); gload16(_g + (size_t)8*K, _l + 512); } while(0)
#define STAGE_B(t,h) do { \
    const unsigned short* _g = Bt + (size_t)(n0 + (h)*128 + w*16 + lrow) * K + (size_t)((t)*64 + sslot8); \
    unsigned short* _l = &Bs[((((t)&1)*256 + (h)*128 + w*16)) * 64]; \
    gload16(_g, _l); gload16(_g + (size_t)8*K, _l + 512); } while(0)
#define LDA(buf,m,ks) __builtin_bit_cast(bf16x8, *(const u16x8*)(&As[(buf)*16384 + (rA + (m)*16)*64 + ((((ks)*4 + qq) ^ sxor) << 3)]))
#define LDB(buf,n,ks) __builtin_bit_cast(bf16x8, *(const u16x8*)(&Bs[(buf)*16384 + (rB + (n)*16)*64 + ((((ks)*4 + qq) ^ sxor) << 3)]))
#define MFMA_Q(AV,MBASE,NLO) \
    _Pragma("unroll") for (int _m = 0; _m < 4; _m++) \
    _Pragma("unroll") for (int _n = 0; _n < 2; _n++) \
    _Pragma("unroll") for (int _k = 0; _k < 2; _k++) \
      acc[(MBASE)+_m][(NLO)+_n] = __builtin_amdgcn_mfma_f32_16x16x32_bf16( \
          AV[_m][_k], bv[(NLO)+_n][_k], acc[(MBASE)+_m][(NLO)+_n], 0, 0, 0);

  f32x4 acc[8][4] = {};
  bf16x8 av0[4][2], av1[4][2], bv[4][2];

  // prologue: tile0 (B0,B1,A0,A1) + tile1 (B0,B1,A0) = 14 loads/wave
  STAGE_B(0,0); STAGE_B(0,1); STAGE_A(0,0); STAGE_A(0,1);
  STAGE_B(1,0); STAGE_B(1,1); STAGE_A(1,0);
  asm volatile("s_waitcnt vmcnt(6)" ::: "memory");   // tile0 fully landed
  __builtin_amdgcn_s_barrier();

  for (int t = 0; t < nt; ++t) {
    const int cur = t & 1;
    // ---- phase 0
#pragma unroll
    for (int n = 0; n < 4; n++) { bv[n][0] = LDB(cur,n,0); bv[n][1] = LDB(cur,n,1); }
#pragma unroll
    for (int m = 0; m < 4; m++) { av0[m][0] = LDA(cur,m,0); av0[m][1] = LDA(cur,m,1); }
    if (t + 1 < nt) STAGE_A(t+1, 1);
    __builtin_amdgcn_s_barrier();
    __builtin_amdgcn_s_setprio(1);
    MFMA_Q(av0, 0, 0);
    __builtin_amdgcn_s_setprio(0);
    __builtin_amdgcn_s_barrier();
    // ---- phase 1
#pragma unroll
    for (int m = 0; m < 4; m++) { av1[m][0] = LDA(cur,m+4,0); av1[m][1] = LDA(cur,m+4,1); }
    if (t + 2 < nt) STAGE_B(t+2, 0);
    __builtin_amdgcn_s_barrier();
    __builtin_amdgcn_s_setprio(1);
    MFMA_Q(av0, 0, 2);
    __builtin_amdgcn_s_setprio(0);
    __builtin_amdgcn_s_barrier();
    // ---- phase 2
    if (t + 2 < nt) STAGE_B(t+2, 1);
    __builtin_amdgcn_s_barrier();
    __builtin_amdgcn_s_setprio(1);
    MFMA_Q(av1, 4, 0);
    __builtin_amdgcn_s_setprio(0);
    __builtin_amdgcn_s_barrier();
    // ---- phase 3
    if (t + 2 < nt) STAGE_A(t+2, 0);
    __builtin_amdgcn_s_barrier();
    __builtin_amdgcn_s_setprio(1);
    MFMA_Q(av1, 4, 2);
    __builtin_amdgcn_s_setprio(0);
    if (t < nt - 2) asm volatile("s_waitcnt vmcnt(6)" ::: "memory");
    else            asm volatile("s_waitcnt vmcnt(0)" ::: "memory");
    __builtin_amdgcn_s_barrier();
  }

  float* Cfz = Cf ? Cf + (size_t)tz * sC : nullptr;
  unsigned short* Cbz = Cb ? Cb + (size_t)tz * sC : nullptr;
#pragma unroll
  for (int n = 0; n < 4; n++) {
    const int col = n0 + wc * 64 + n * 16 + (lane & 15);
    const float bvv = bias ? bias[col] : 0.0f;
#pragma unroll
    for (int m = 0; m < 8; m++) {
      const int row = m0 + wr * 128 + m * 16 + (lane >> 4) * 4;
#pragma unroll
      for (int r = 0; r < 4; r++) {
        float v = (acc[m][n][r] + bvv) * alpha;
        if (OUT_BF16) Cbz[(size_t)(row + r) * N + col] = f32_to_bf16(v);
        else          Cfz[(size_t)(row + r) * N + col] = v;
      }
    }
  }
#undef STAGE_A
#undef STAGE_B
#undef LDA
#undef LDB
#undef MFMA_Q
}

// ---- row softmax: S fp32 [rows][2048] -> P bf16 [rows][2048] ----
__global__ __launch_bounds__(256) void softmax_kernel(
    const float* __restrict__ S, unsigned short* __restrict__ P) {
  const int row = blockIdx.x;
  const float* sp = S + (size_t)row * SD;
  const int tid = threadIdx.x, lane = tid & 63, w = tid >> 6;
  float4 v0 = *(const float4*)(sp + tid * 8);
  float4 v1 = *(const float4*)(sp + tid * 8 + 4);
  float x[8] = {v0.x,v0.y,v0.z,v0.w,v1.x,v1.y,v1.z,v1.w};
  float m = x[0];
#pragma unroll
  for (int j = 1; j < 8; j++) m = fmaxf(m, x[j]);
#pragma unroll
  for (int off = 32; off >= 1; off >>= 1) m = fmaxf(m, __shfl_xor(m, off));
  __shared__ float redm[4];
  if (lane == 0) redm[w] = m;
  __syncthreads();
  m = fmaxf(fmaxf(redm[0], redm[1]), fmaxf(redm[2], redm[3]));
  float e[8]; float s = 0.0f;
#pragma unroll
  for (int j = 0; j < 8; j++) { e[j] = __expf(x[j] - m); s += e[j]; }
#pragma unroll
  for (int off = 32; off >= 1; off >>= 1) s += __shfl_xor(s, off);
  __shared__ float reds[4];
  if (lane == 0) reds[w] = s;
  __syncthreads();
  s = reds[0] + reds[1] + reds[2] + reds[3];
  const float inv = 1.0f / s;
  u16x8 o;
#pragma unroll
  for (int j = 0; j < 8; j++) o[j] = f32_to_bf16(e[j] * inv);
  *(u16x8*)(P + (size_t)row * SD + tid * 8) = o;
}

// ---- launch ----
extern "C" void kernel_launch(void* const* d_in, const int* in_sizes, int n_in,
                              void* d_out, int out_size, void* d_ws, size_t ws_size,
                              hipStream_t stream) {
  const float* x  = (const float*)d_in[0];
  const float* Wq = (const float*)d_in[1];
  const float* bq = (const float*)d_in[2];
  const float* Wk = (const float*)d_in[3];
  const float* bk = (const float*)d_in[4];
  const float* Wv = (const float*)d_in[5];
  const float* bv = (const float*)d_in[6];
  float* out = (float*)d_out;
  char* ws = (char*)d_ws;
  const size_t MB = 1024 * 1024;
  const float scale = 0.03125f;              // 1/sqrt(1024)
  const size_t BH = (size_t)SD * HD;         // 2M elems (one batch of Q/K/V)
  const size_t SS = (size_t)SD * SD;         // 4M elems (one batch of scores/P)

  // layout: wt 0-6 | Qb 6-38 | Kb 38-70 | Vb 70-102 | xb 102-134 (->Vt after
  // proj) | scores fp32 134-(134+16G) | P bf16 over dead Vb at 70 (or @198 pv8)
  unsigned short* wt = (unsigned short*)(ws + 0);
  unsigned short* Qb = (unsigned short*)(ws + 6 * MB);
  unsigned short* Kb = (unsigned short*)(ws + 38 * MB);
  unsigned short* Vb = (unsigned short*)(ws + 70 * MB);
  unsigned short* xb = (unsigned short*)(ws + 102 * MB);
  unsigned short* Vt = (unsigned short*)(ws + 102 * MB);   // xb dead by then
  float* scores      = (float*)(ws + 134 * MB);

  int G; bool pv8;
  if      (ws_size >= 262 * MB) { G = 4; pv8 = true;  }
  else if (ws_size >= 198 * MB) { G = 4; pv8 = false; }
  else if (ws_size >= 166 * MB) { G = 2; pv8 = false; }
  else                          { G = 1; pv8 = false; }   // needs 150 MB
  unsigned short* P = (unsigned short*)(ws + (pv8 ? 198 * MB : 70 * MB));

  transpose_w_kernel<<<dim3(32, 32, 3), dim3(32, 8), 0, stream>>>(Wq, Wk, Wv, wt);
  cast_x_kernel<<<8192, 256, 0, stream>>>(x, xb);

  // fused QKV projection: z = weight index, M = 16384 (grid 4x64x3 = 768)
  gemm256<1><<<dim3(HD/256, (BD*SD)/256, 3), 512, 0, stream>>>(
      xb, 0, wt, (size_t)HD*HD, bq, bk, bv,
      nullptr, Qb, (size_t)16*MB, BD*SD, HD, HD, 1.0f);

  transpose_v_kernel<<<dim3(HD/32, SD/32, BD), dim3(32, 8), 0, stream>>>(Vb, Vt);

  const int ngroups = BD / G;
  for (int g = 0; g < ngroups; g++) {
    // scores = scale * Q K^T   (z = batch within group)
    gemm256<0><<<dim3(SD/256, SD/256, G), 512, 0, stream>>>(
        Qb + (size_t)g*G*BH, BH, Kb + (size_t)g*G*BH, BH,
        nullptr, nullptr, nullptr, scores, nullptr, SS, SD, SD, HD, scale);
    softmax_kernel<<<G*SD, 256, 0, stream>>>(
        scores, P + (pv8 ? (size_t)g*G*SS : 0));
    if (!pv8) {
      gemm256<0><<<dim3(HD/256, SD/256, G), 512, 0, stream>>>(
          P, SS, Vt + (size_t)g*G*BH, BH, nullptr, nullptr, nullptr,
          out + (size_t)g*G*BH, nullptr, BH, SD, HD, SD, 1.0f);
    }
  }
  if (pv8) {
    gemm256<0><<<dim3(HD/256, SD/256, BD), 512, 0, stream>>>(
        P, SS, Vt, BH, nullptr, nullptr, nullptr,
        out, nullptr, BH, SD, HD, SD, 1.0f);
  }
}

// Round 8
// 308.710 us; speedup vs baseline: 4.3040x; 1.3093x over previous
//
#include <hip/hip_runtime.h>
#include <stdint.h>

// B=8, S=2048, H=1024. fp32 in, fp32 out. bf16 MFMA compute core.
#define BD 8
#define SD 2048
#define HD 1024

typedef __bf16 bf16x8 __attribute__((ext_vector_type(8)));
typedef float f32x4 __attribute__((ext_vector_type(4)));
typedef unsigned short u16x8 __attribute__((ext_vector_type(8)));

typedef const __attribute__((address_space(1))) void* gas_ptr;
typedef __attribute__((address_space(3))) void* las_ptr;

__device__ __forceinline__ void gload16(const void* g, void* l) {
  __builtin_amdgcn_global_load_lds((gas_ptr)g, (las_ptr)l, 16, 0, 0);
}

__device__ __forceinline__ unsigned short f32_to_bf16(float f) {
  union { float f; unsigned u; } v; v.f = f;
  unsigned u = v.u;
  return (unsigned short)((u + 0x7FFFu + ((u >> 16) & 1u)) >> 16);  // RNE
}
__device__ __forceinline__ float bf16_to_f32(unsigned short h) {
  union { unsigned u; float f; } v; v.u = ((unsigned)h) << 16;
  return v.f;
}

// ---- cast x: fp32 -> bf16 ----
__global__ __launch_bounds__(256) void cast_x_kernel(
    const float* __restrict__ x, unsigned short* __restrict__ xb) {
  size_t i = (size_t)blockIdx.x * 256 + threadIdx.x;
  const float4* xp = (const float4*)x;
  float4 a = xp[2*i], b = xp[2*i + 1];
  float v[8] = {a.x,a.y,a.z,a.w,b.x,b.y,b.z,b.w};
  u16x8 o;
#pragma unroll
  for (int j = 0; j < 8; j++) o[j] = f32_to_bf16(v[j]);
  *(u16x8*)(xb + i*8) = o;
}

// ---- W [K][N] fp32 -> W^T bf16 [N][K], 3 weights via blockIdx.z ----
__global__ __launch_bounds__(256) void transpose_w_kernel(
    const float* __restrict__ Wq, const float* __restrict__ Wk,
    const float* __restrict__ Wv, unsigned short* __restrict__ wt) {
  __shared__ float tile[32][33];
  const int w = blockIdx.z;
  const float* W = (w == 0) ? Wq : ((w == 1) ? Wk : Wv);
  const int n0 = blockIdx.x * 32, k0 = blockIdx.y * 32;
  const int x = threadIdx.x, y = threadIdx.y;       // block (32,8)
  for (int j = 0; j < 32; j += 8)
    tile[y + j][x] = W[(size_t)(k0 + y + j) * HD + n0 + x];
  __syncthreads();
  unsigned short* dst = wt + (size_t)w * HD * HD;
  for (int j = 0; j < 32; j += 8)
    dst[(size_t)(n0 + y + j) * HD + k0 + x] = f32_to_bf16(tile[x][y + j]);
}

// ---- V [z][2048][1024] bf16 -> Vt [z][1024][2048] bf16 ----
__global__ __launch_bounds__(256) void transpose_v_kernel(
    const unsigned short* __restrict__ V, unsigned short* __restrict__ Vt) {
  __shared__ unsigned short tile[32][33];
  const unsigned short* Vz = V + (size_t)blockIdx.z * SD * HD;
  unsigned short* Vtz = Vt + (size_t)blockIdx.z * HD * SD;
  const int h0 = blockIdx.x * 32, s0 = blockIdx.y * 32;
  const int x = threadIdx.x, y = threadIdx.y;       // block (32,8)
  for (int j = 0; j < 32; j += 8)
    tile[y + j][x] = Vz[(size_t)(s0 + y + j) * HD + h0 + x];
  __syncthreads();
  for (int j = 0; j < 32; j += 8)
    Vtz[(size_t)(h0 + y + j) * SD + s0 + x] = tile[x][y + j];
}

// ---- 256x256 8-phase GEMM (m201-skeleton, verified r7: 0 bank conflicts) ----
// Round-8 change: OUT_BF16 epilogue stages each wave's 128x64 tile in its
// private LDS slice (reusing As/Bs after the final barrier) and stores
// 16B/lane coalesced — fixes the measured 2.4x HBM write amplification.
template<int OUT_BF16>
__global__ __launch_bounds__(512, 2) void gemm256(
    const unsigned short* __restrict__ A, size_t sA,
    const unsigned short* __restrict__ Bt, size_t sB,
    const float* __restrict__ b0, const float* __restrict__ b1,
    const float* __restrict__ b2,
    float* __restrict__ Cf, unsigned short* __restrict__ Cb, size_t sC,
    int M, int N, int K, float alpha)
{
  __shared__ unsigned short As[2 * 256 * 64];   // 64 KB
  __shared__ unsigned short Bs[2 * 256 * 64];   // 64 KB

  // bijective XCD swizzle over flattened grid (all grids % 8 == 0)
  const int gx = gridDim.x, gy = gridDim.y;
  const int nwg = gx * gy * gridDim.z;
  const int flat = blockIdx.x + gx * (blockIdx.y + gy * blockIdx.z);
  const int swz = (flat & 7) * (nwg >> 3) + (flat >> 3);
  const int tz = swz / (gx * gy);
  const int rem = swz - tz * gx * gy;
  const int ty = rem / gx, tx = rem - (rem / gx) * gx;
  const int m0 = ty * 256, n0 = tx * 256;

  A  += (size_t)tz * sA;
  Bt += (size_t)tz * sB;
  const float* bias = (tz == 0) ? b0 : ((tz == 1) ? b1 : b2);

  const int tid = threadIdx.x, lane = tid & 63, w = tid >> 6;  // 8 waves
  const int wr = w >> 2, wc = w & 3;          // 2 x 4 wave grid
  const int nt = K >> 6;                      // BK=64 tiles

  // staging: lane covers row (base + lane>>3), physical 16B slot lane&7;
  // source logical slot = (lane&7) ^ (row&7)  (full-row XOR, r7-verified)
  const int lrow = lane >> 3;
  const int sslot8 = (((lane & 7) ^ ((lane >> 3) & 7)) << 3);

  const int rA = wr * 128 + (lane & 15);
  const int rB = wc * 64 + (lane & 15);
  const int qq = lane >> 4;
  const int sxor = lane & 7;

#define STAGE_A(t,h) do { \
    const unsigned short* _g = A + (size_t)(m0 + (h)*128 + w*16 + lrow) * K + (size_t)((t)*64 + sslot8); \
    unsigned short* _l = &As[((((t)&1)*256 + (h)*128 + w*16)) * 64]; \
    gload16(_g, _l); gload16(_g + (size_t)8*K, _l + 512); } while(0)
#define STAGE_B(t,h) do { \
    const unsigned short* _g = Bt + (size_t)(n0 + (h)*128 + w*16 + lrow) * K + (size_t)((t)*64 + sslot8); \
    unsigned short* _l = &Bs[((((t)&1)*256 + (h)*128 + w*16)) * 64]; \
    gload16(_g, _l); gload16(_g + (size_t)8*K, _l + 512); } while(0)
#define LDA(buf,m,ks) __builtin_bit_cast(bf16x8, *(const u16x8*)(&As[(buf)*16384 + (rA + (m)*16)*64 + ((((ks)*4 + qq) ^ sxor) << 3)]))
#define LDB(buf,n,ks) __builtin_bit_cast(bf16x8, *(const u16x8*)(&Bs[(buf)*16384 + (rB + (n)*16)*64 + ((((ks)*4 + qq) ^ sxor) << 3)]))
#define MFMA_Q(AV,MBASE,NLO) \
    _Pragma("unroll") for (int _m = 0; _m < 4; _m++) \
    _Pragma("unroll") for (int _n = 0; _n < 2; _n++) \
    _Pragma("unroll") for (int _k = 0; _k < 2; _k++) \
      acc[(MBASE)+_m][(NLO)+_n] = __builtin_amdgcn_mfma_f32_16x16x32_bf16( \
          AV[_m][_k], bv[(NLO)+_n][_k], acc[(MBASE)+_m][(NLO)+_n], 0, 0, 0);

  f32x4 acc[8][4] = {};
  bf16x8 av0[4][2], av1[4][2], bv[4][2];

  STAGE_B(0,0); STAGE_B(0,1); STAGE_A(0,0); STAGE_A(0,1);
  STAGE_B(1,0); STAGE_B(1,1); STAGE_A(1,0);
  asm volatile("s_waitcnt vmcnt(6)" ::: "memory");
  __builtin_amdgcn_s_barrier();

  for (int t = 0; t < nt; ++t) {
    const int cur = t & 1;
    // ---- phase 0
#pragma unroll
    for (int n = 0; n < 4; n++) { bv[n][0] = LDB(cur,n,0); bv[n][1] = LDB(cur,n,1); }
#pragma unroll
    for (int m = 0; m < 4; m++) { av0[m][0] = LDA(cur,m,0); av0[m][1] = LDA(cur,m,1); }
    if (t + 1 < nt) STAGE_A(t+1, 1);
    __builtin_amdgcn_s_barrier();
    __builtin_amdgcn_s_setprio(1);
    MFMA_Q(av0, 0, 0);
    __builtin_amdgcn_s_setprio(0);
    __builtin_amdgcn_s_barrier();
    // ---- phase 1
#pragma unroll
    for (int m = 0; m < 4; m++) { av1[m][0] = LDA(cur,m+4,0); av1[m][1] = LDA(cur,m+4,1); }
    if (t + 2 < nt) STAGE_B(t+2, 0);
    __builtin_amdgcn_s_barrier();
    __builtin_amdgcn_s_setprio(1);
    MFMA_Q(av0, 0, 2);
    __builtin_amdgcn_s_setprio(0);
    __builtin_amdgcn_s_barrier();
    // ---- phase 2
    if (t + 2 < nt) STAGE_B(t+2, 1);
    __builtin_amdgcn_s_barrier();
    __builtin_amdgcn_s_setprio(1);
    MFMA_Q(av1, 4, 0);
    __builtin_amdgcn_s_setprio(0);
    __builtin_amdgcn_s_barrier();
    // ---- phase 3
    if (t + 2 < nt) STAGE_A(t+2, 0);
    __builtin_amdgcn_s_barrier();
    __builtin_amdgcn_s_setprio(1);
    MFMA_Q(av1, 4, 2);
    __builtin_amdgcn_s_setprio(0);
    if (t < nt - 2) asm volatile("s_waitcnt vmcnt(6)" ::: "memory");
    else            asm volatile("s_waitcnt vmcnt(0)" ::: "memory");
    __builtin_amdgcn_s_barrier();
  }

  if (OUT_BF16) {
    // coalesced epilogue: wave-private 16KB LDS slice (all main-loop LDS
    // reads drained by the final barrier; each wave touches only its slice)
    unsigned short* Cbz = Cb + (size_t)tz * sC;
    unsigned short* base = (w < 4) ? (As + w * 8192) : (Bs + (w - 4) * 8192);
    float bvv[4];
#pragma unroll
    for (int n = 0; n < 4; n++)
      bvv[n] = bias ? bias[n0 + wc * 64 + n * 16 + (lane & 15)] : 0.0f;
#pragma unroll
    for (int n = 0; n < 4; n++)
#pragma unroll
      for (int m = 0; m < 8; m++)
#pragma unroll
        for (int r = 0; r < 4; r++) {
          const int lr = m * 16 + (lane >> 4) * 4 + r;
          const int lc = n * 16 + (lane & 15);
          base[lr * 64 + lc] = f32_to_bf16((acc[m][n][r] + bvv[n]) * alpha);
        }
#pragma unroll
    for (int i = 0; i < 16; i++) {
      const int lr = i * 8 + (lane >> 3);
      u16x8 vrow = *(const u16x8*)(base + lr * 64 + (lane & 7) * 8);
      *(u16x8*)(Cbz + (size_t)(m0 + wr * 128 + lr) * N
                + (n0 + wc * 64 + (lane & 7) * 8)) = vrow;
    }
  } else {
    float* Cfz = Cf + (size_t)tz * sC;
#pragma unroll
    for (int n = 0; n < 4; n++) {
      const int col = n0 + wc * 64 + n * 16 + (lane & 15);
      const float bvv = bias ? bias[col] : 0.0f;
#pragma unroll
      for (int m = 0; m < 8; m++) {
        const int row = m0 + wr * 128 + m * 16 + (lane >> 4) * 4;
#pragma unroll
        for (int r = 0; r < 4; r++)
          Cfz[(size_t)(row + r) * N + col] = (acc[m][n][r] + bvv) * alpha;
      }
    }
  }
#undef STAGE_A
#undef STAGE_B
#undef LDA
#undef LDB
#undef MFMA_Q
}

// ---- in-place row softmax on bf16 scores: S [rows][2048] bf16 ----
__global__ __launch_bounds__(256) void softmax_bf16_kernel(
    unsigned short* __restrict__ S) {
  const int row = blockIdx.x;
  unsigned short* sp = S + (size_t)row * SD;
  const int tid = threadIdx.x, lane = tid & 63, w = tid >> 6;
  u16x8 raw = *(const u16x8*)(sp + tid * 8);
  float x[8];
#pragma unroll
  for (int j = 0; j < 8; j++) x[j] = bf16_to_f32(raw[j]);
  float m = x[0];
#pragma unroll
  for (int j = 1; j < 8; j++) m = fmaxf(m, x[j]);
#pragma unroll
  for (int off = 32; off >= 1; off >>= 1) m = fmaxf(m, __shfl_xor(m, off));
  __shared__ float redm[4];
  if (lane == 0) redm[w] = m;
  __syncthreads();
  m = fmaxf(fmaxf(redm[0], redm[1]), fmaxf(redm[2], redm[3]));
  float e[8]; float s = 0.0f;
#pragma unroll
  for (int j = 0; j < 8; j++) { e[j] = __expf(x[j] - m); s += e[j]; }
#pragma unroll
  for (int off = 32; off >= 1; off >>= 1) s += __shfl_xor(s, off);
  __shared__ float reds[4];
  if (lane == 0) reds[w] = s;
  __syncthreads();
  s = reds[0] + reds[1] + reds[2] + reds[3];
  const float inv = 1.0f / s;
  u16x8 o;
#pragma unroll
  for (int j = 0; j < 8; j++) o[j] = f32_to_bf16(e[j] * inv);
  *(u16x8*)(sp + tid * 8) = o;
}

// ---- launch ----
extern "C" void kernel_launch(void* const* d_in, const int* in_sizes, int n_in,
                              void* d_out, int out_size, void* d_ws, size_t ws_size,
                              hipStream_t stream) {
  const float* x  = (const float*)d_in[0];
  const float* Wq = (const float*)d_in[1];
  const float* bq = (const float*)d_in[2];
  const float* Wk = (const float*)d_in[3];
  const float* bk = (const float*)d_in[4];
  const float* Wv = (const float*)d_in[5];
  const float* bv = (const float*)d_in[6];
  float* out = (float*)d_out;
  char* ws = (char*)d_ws;
  const size_t MB = 1024 * 1024;
  const float scale = 0.03125f;              // 1/sqrt(1024)
  const size_t BH = (size_t)SD * HD;         // 2M elems (one batch of Q/K/V)
  const size_t SS = (size_t)SD * SD;         // 4M elems (one batch of scores)

  // layout: wt 0-6 | Qb 6-38 | Kb 38-70 | Vb 70-102 | xb/Vt 102-134 |
  // scores/P bf16 (in-place softmax) 134-(134 + 8*G) MB
  unsigned short* wt = (unsigned short*)(ws + 0);
  unsigned short* Qb = (unsigned short*)(ws + 6 * MB);
  unsigned short* Kb = (unsigned short*)(ws + 38 * MB);
  unsigned short* Vb = (unsigned short*)(ws + 70 * MB);
  unsigned short* xb = (unsigned short*)(ws + 102 * MB);
  unsigned short* Vt = (unsigned short*)(ws + 102 * MB);   // xb dead by then
  unsigned short* Pb = (unsigned short*)(ws + 134 * MB);   // bf16 scores/P

  int G;
  if      (ws_size >= 198 * MB) G = 8;
  else if (ws_size >= 166 * MB) G = 4;
  else if (ws_size >= 150 * MB) G = 2;
  else                          G = 1;       // needs 142 MB

  transpose_w_kernel<<<dim3(32, 32, 3), dim3(32, 8), 0, stream>>>(Wq, Wk, Wv, wt);
  cast_x_kernel<<<8192, 256, 0, stream>>>(x, xb);

  // fused QKV projection: z = weight index, M = 16384
  gemm256<1><<<dim3(HD/256, (BD*SD)/256, 3), 512, 0, stream>>>(
      xb, 0, wt, (size_t)HD*HD, bq, bk, bv,
      nullptr, Qb, (size_t)16*MB, BD*SD, HD, HD, 1.0f);

  transpose_v_kernel<<<dim3(HD/32, SD/32, BD), dim3(32, 8), 0, stream>>>(Vb, Vt);

  const int ngroups = BD / G;
  for (int g = 0; g < ngroups; g++) {
    // scores = scale * Q K^T  (bf16 out via coalesced epilogue)
    gemm256<1><<<dim3(SD/256, SD/256, G), 512, 0, stream>>>(
        Qb + (size_t)g*G*BH, BH, Kb + (size_t)g*G*BH, BH,
        nullptr, nullptr, nullptr, nullptr, Pb, SS, SD, SD, HD, scale);
    softmax_bf16_kernel<<<G*SD, 256, 0, stream>>>(Pb);
    // out = P V   (fp32 out, coalesced 64B chunks)
    gemm256<0><<<dim3(HD/256, SD/256, G), 512, 0, stream>>>(
        Pb, SS, Vt + (size_t)g*G*BH, BH, nullptr, nullptr, nullptr,
        out + (size_t)g*G*BH, nullptr, BH, SD, HD, SD, 1.0f);
  }
}